// Round 3
// baseline (1020.829 us; speedup 1.0000x reference)
//
#include <hip/hip_runtime.h>

// GraphSAGE forward: CSR build (count/scan/scatter) + 4 fused level kernels
// (mean-agg + 2 register-tiled small GEMMs) + output projection. All f32.
//
// Level kernel: 8-lane groups gather one node each (float4 rows, direct
// uniform index loads, 4-edge unroll) -> 8 nodes per wave. GEMMs are
// wave-private register-tiled: lane = (node-part, col-quad), per k:
// 1 ds_read_b128 (weights, broadcast) + NACC ds_read_b32 (m, broadcast)
// + 4*NACC fmac. sM/sA share one padded LDS buffer (wave-private ordering).

__device__ inline void f4acc(float4& a, const float4& b) {
    a.x += b.x; a.y += b.y; a.z += b.z; a.w += b.w;
}

__global__ __launch_bounds__(256) void k_count(const int* __restrict__ edst,
                                               int* __restrict__ deg, int E) {
    int t = blockIdx.x * blockDim.x + threadIdx.x;
    if (t < E) atomicAdd(&deg[edst[t]], 1);
}

__global__ __launch_bounds__(256) void k_blocksum(const int* __restrict__ deg,
                                                  int* __restrict__ bsums, int N) {
    __shared__ int s[256];
    int t = threadIdx.x;
    int base = blockIdx.x * 1024 + t * 4;
    int v = 0;
#pragma unroll
    for (int j = 0; j < 4; j++) { int idx = base + j; if (idx < N) v += deg[idx]; }
    s[t] = v; __syncthreads();
    for (int o = 128; o > 0; o >>= 1) { if (t < o) s[t] += s[t + o]; __syncthreads(); }
    if (t == 0) bsums[blockIdx.x] = s[0];
}

__global__ __launch_bounds__(256) void k_scantop(int* __restrict__ bsums, int NB) {
    __shared__ int s[256];
    int t = threadIdx.x;
    int v = (t < NB) ? bsums[t] : 0;
    s[t] = v; __syncthreads();
    for (int o = 1; o < 256; o <<= 1) {
        int x = (t >= o) ? s[t - o] : 0;
        __syncthreads();
        s[t] += x;
        __syncthreads();
    }
    if (t < NB) bsums[t] = s[t] - v;
}

__global__ __launch_bounds__(256) void k_scanfinal(const int* __restrict__ deg,
                                                   const int* __restrict__ bsums,
                                                   int* __restrict__ offsets,
                                                   int* __restrict__ cursor,
                                                   float* __restrict__ inv_cnt,
                                                   int N, int E) {
    __shared__ int s[256];
    int t = threadIdx.x, b = blockIdx.x;
    int base = b * 1024 + t * 4;
    int d[4]; int lsum = 0;
#pragma unroll
    for (int j = 0; j < 4; j++) { int idx = base + j; d[j] = (idx < N) ? deg[idx] : 0; lsum += d[j]; }
    s[t] = lsum; __syncthreads();
    for (int o = 1; o < 256; o <<= 1) {
        int x = (t >= o) ? s[t - o] : 0;
        __syncthreads();
        s[t] += x;
        __syncthreads();
    }
    int p = bsums[b] + s[t] - lsum;
#pragma unroll
    for (int j = 0; j < 4; j++) {
        int idx = base + j;
        if (idx < N) {
            offsets[idx] = p;
            cursor[idx] = p;
            inv_cnt[idx] = 1.0f / (float)(d[j] > 0 ? d[j] : 1);
            p += d[j];
        }
    }
    if (b == 0 && t == 0) offsets[N] = E;
}

__global__ __launch_bounds__(256) void k_scatter(const int* __restrict__ esrc,
                                                 const int* __restrict__ edst,
                                                 int* __restrict__ cursor,
                                                 int* __restrict__ csr, int E) {
    int t = blockIdx.x * blockDim.x + threadIdx.x;
    if (t < E) {
        int d = edst[t];
        int pos = atomicAdd(&cursor[d], 1);
        csr[pos] = esrc[t];
    }
}

// Wave-private register-tiled GEMM: [8 nodes x DC cols] = wMA[8][K] @ W[K][DC].
// Lane = (part = lane/CQ, quad q = lane%CQ); NACC = 8/PARTS nodes per lane.
template <int K, int DC, int PADM>
__device__ inline void wave_gemm_lds(const float* wMA, const float* __restrict__ W,
                                     float* outLDS, int lane) {
    constexpr int CQ = DC / 4;
    constexpr int PARTS = 64 / CQ;
    constexpr int NACC = 8 / PARTS;
    const int q = lane & (CQ - 1);
    const int part = lane / CQ;
    float4 acc[NACC];
#pragma unroll
    for (int j = 0; j < NACC; ++j) acc[j] = make_float4(0.f, 0.f, 0.f, 0.f);
#pragma unroll
    for (int k = 0; k < K; ++k) {
        float4 w = *(const float4*)&W[k * DC + 4 * q];
#pragma unroll
        for (int j = 0; j < NACC; ++j) {
            float mv = wMA[(part + j * PARTS) * PADM + k];
            acc[j].x += mv * w.x; acc[j].y += mv * w.y;
            acc[j].z += mv * w.z; acc[j].w += mv * w.w;
        }
    }
#pragma unroll
    for (int j = 0; j < NACC; ++j) {
        float4 r = make_float4(fmaxf(acc[j].x, 0.f), fmaxf(acc[j].y, 0.f),
                               fmaxf(acc[j].z, 0.f), fmaxf(acc[j].w, 0.f));
        *(float4*)&outLDS[(part + j * PARTS) * PADM + 4 * q] = r;
    }
}

template <int K, int DC, int PADM>
__device__ inline void wave_gemm_out(const float* wMA, const float* __restrict__ W,
                                     float* __restrict__ dst, int nodebase, int N, int lane) {
    constexpr int CQ = DC / 4;
    constexpr int PARTS = 64 / CQ;
    constexpr int NACC = 8 / PARTS;
    const int q = lane & (CQ - 1);
    const int part = lane / CQ;
    float4 acc[NACC];
#pragma unroll
    for (int j = 0; j < NACC; ++j) acc[j] = make_float4(0.f, 0.f, 0.f, 0.f);
#pragma unroll
    for (int k = 0; k < K; ++k) {
        float4 w = *(const float4*)&W[k * DC + 4 * q];
#pragma unroll
        for (int j = 0; j < NACC; ++j) {
            float mv = wMA[(part + j * PARTS) * PADM + k];
            acc[j].x += mv * w.x; acc[j].y += mv * w.y;
            acc[j].z += mv * w.z; acc[j].w += mv * w.w;
        }
    }
#pragma unroll
    for (int j = 0; j < NACC; ++j) {
        int node = nodebase + part + j * PARTS;
        if (node < N) {
            float4 r = make_float4(fmaxf(acc[j].x, 0.f), fmaxf(acc[j].y, 0.f),
                                   fmaxf(acc[j].z, 0.f), fmaxf(acc[j].w, 0.f));
            *(float4*)&dst[(size_t)node * DC + 4 * q] = r;
        }
    }
}

template <int DIN, int DMID, int DOUT, int PADM>
__global__ __launch_bounds__(512, 6) void k_level(
    const float* __restrict__ hprev, float* __restrict__ hnext,
    const int* __restrict__ offsets, const int* __restrict__ csr,
    const float* __restrict__ inv_cnt,
    const float* __restrict__ Wa, const float* __restrict__ We, int N) {
    constexpr int WAVES = 8;
    constexpr int NPG = 8;            // nodes per wave
    constexpr int NPB = WAVES * NPG;  // 64 nodes per block

    __shared__ alignas(16) float sWa[DIN * DMID];
    __shared__ alignas(16) float sWe[DMID * DOUT];
    __shared__ alignas(16) float sMA[NPB * PADM];

    for (int i = threadIdx.x; i < DIN * DMID; i += 512) sWa[i] = Wa[i];
    for (int i = threadIdx.x; i < DMID * DOUT; i += 512) sWe[i] = We[i];
    __syncthreads();

    const int lane = threadIdx.x & 63;
    const int wid  = threadIdx.x >> 6;
    const int g    = lane >> 3;       // node group within wave
    const int lg   = lane & 7;
    float* wMA = sMA + (wid * NPG) * PADM;

    const long stride = (long)gridDim.x * NPB;
    for (long base0 = (long)blockIdx.x * NPB; base0 < N; base0 += stride) {
        const int nodebase = (int)base0 + wid * NPG;
        const int node = nodebase + g;

        // ---- gather + mean ----
        if (node < N) {
            int start = offsets[node], end = offsets[node + 1];
            float4 accA = make_float4(0.f, 0.f, 0.f, 0.f);
            float4 accB = make_float4(0.f, 0.f, 0.f, 0.f);
            float acc1 = 0.f;
            int i = start;
            for (; i + 4 <= end; i += 4) {
                int s0 = csr[i], s1 = csr[i + 1], s2 = csr[i + 2], s3 = csr[i + 3];
                if constexpr (DIN == 64) {
                    const float4* r0 = (const float4*)(hprev + (size_t)s0 * 64);
                    const float4* r1 = (const float4*)(hprev + (size_t)s1 * 64);
                    const float4* r2 = (const float4*)(hprev + (size_t)s2 * 64);
                    const float4* r3 = (const float4*)(hprev + (size_t)s3 * 64);
                    float4 a0 = r0[2 * lg], b0 = r0[2 * lg + 1];
                    float4 a1 = r1[2 * lg], b1 = r1[2 * lg + 1];
                    float4 a2 = r2[2 * lg], b2 = r2[2 * lg + 1];
                    float4 a3 = r3[2 * lg], b3 = r3[2 * lg + 1];
                    f4acc(accA, a0); f4acc(accB, b0);
                    f4acc(accA, a1); f4acc(accB, b1);
                    f4acc(accA, a2); f4acc(accB, b2);
                    f4acc(accA, a3); f4acc(accB, b3);
                } else if constexpr (DIN == 32) {
                    const float4* r0 = (const float4*)(hprev + (size_t)s0 * 32);
                    const float4* r1 = (const float4*)(hprev + (size_t)s1 * 32);
                    const float4* r2 = (const float4*)(hprev + (size_t)s2 * 32);
                    const float4* r3 = (const float4*)(hprev + (size_t)s3 * 32);
                    float4 a0 = r0[lg], a1 = r1[lg], a2 = r2[lg], a3 = r3[lg];
                    f4acc(accA, a0); f4acc(accA, a1);
                    f4acc(accA, a2); f4acc(accA, a3);
                } else {  // DIN == 3
                    if (lg < 3) {
                        acc1 += hprev[(size_t)s0 * 3 + lg];
                        acc1 += hprev[(size_t)s1 * 3 + lg];
                        acc1 += hprev[(size_t)s2 * 3 + lg];
                        acc1 += hprev[(size_t)s3 * 3 + lg];
                    }
                }
            }
            for (; i < end; ++i) {
                int s0 = csr[i];
                if constexpr (DIN == 64) {
                    const float4* r0 = (const float4*)(hprev + (size_t)s0 * 64);
                    f4acc(accA, r0[2 * lg]); f4acc(accB, r0[2 * lg + 1]);
                } else if constexpr (DIN == 32) {
                    const float4* r0 = (const float4*)(hprev + (size_t)s0 * 32);
                    f4acc(accA, r0[lg]);
                } else {
                    if (lg < 3) acc1 += hprev[(size_t)s0 * 3 + lg];
                }
            }
            float ic = inv_cnt[node];
            if constexpr (DIN == 64) {
                accA.x *= ic; accA.y *= ic; accA.z *= ic; accA.w *= ic;
                accB.x *= ic; accB.y *= ic; accB.z *= ic; accB.w *= ic;
                *(float4*)&wMA[g * PADM + 8 * lg]     = accA;
                *(float4*)&wMA[g * PADM + 8 * lg + 4] = accB;
            } else if constexpr (DIN == 32) {
                accA.x *= ic; accA.y *= ic; accA.z *= ic; accA.w *= ic;
                *(float4*)&wMA[g * PADM + 4 * lg] = accA;
            } else {
                if (lg < 3) wMA[g * PADM + lg] = acc1 * ic;
            }
        }

        // ---- a = relu(m @ Wa) ----  (wave-private; writes alias wMA after reads)
        wave_gemm_lds<DIN, DMID, PADM>(wMA, sWa, wMA, lane);
        // ---- h = relu(a @ We) -> global ----
        wave_gemm_out<DMID, DOUT, PADM>(wMA, sWe, hnext, nodebase, N, lane);
    }
}

__global__ __launch_bounds__(256) void k_out(const float* __restrict__ h,
                                             const int* __restrict__ nodes,
                                             const float* __restrict__ Wout,
                                             float* __restrict__ out, int B) {
    __shared__ float sW[32 * 40];
    for (int i = threadIdx.x; i < 32 * 40; i += blockDim.x) sW[i] = Wout[i];
    __syncthreads();
    int t = blockIdx.x * blockDim.x + threadIdx.x;
    if (t >= B * 40) return;
    int i = t / 40, c = t - i * 40;
    const float* e = h + (long)nodes[i] * 32;
    float s = 0.f;
#pragma unroll
    for (int k = 0; k < 32; k++) s += e[k] * sW[k * 40 + c];
    out[t] = s;
}

extern "C" void kernel_launch(void* const* d_in, const int* in_sizes, int n_in,
                              void* d_out, int out_size, void* d_ws, size_t ws_size,
                              hipStream_t stream) {
    const float* raw  = (const float*)d_in[0];
    const int* nodes  = (const int*)d_in[1];
    const int* esrc   = (const int*)d_in[2];
    const int* edst   = (const int*)d_in[3];
    const float* Wa1 = (const float*)d_in[4];
    const float* Wa2 = (const float*)d_in[5];
    const float* Wa3 = (const float*)d_in[6];
    const float* Wa4 = (const float*)d_in[7];
    const float* We1 = (const float*)d_in[8];
    const float* We2 = (const float*)d_in[9];
    const float* We3 = (const float*)d_in[10];
    const float* We4 = (const float*)d_in[11];
    const float* Wout = (const float*)d_in[12];
    float* out = (float*)d_out;

    int N = in_sizes[1];   // 50000
    int E = in_sizes[2];   // 850000
    int B = N;

    char* p = (char*)d_ws;
    auto alloc = [&](size_t bytes) -> char* {
        char* r = p;
        p += (bytes + 255) & ~(size_t)255;
        return r;
    };
    int*   deg     = (int*)alloc((size_t)N * 4);
    int*   offsets = (int*)alloc((size_t)(N + 1) * 4);
    int*   cursor  = (int*)alloc((size_t)N * 4);
    float* inv_cnt = (float*)alloc((size_t)N * 4);
    int NB = (N + 1023) / 1024;
    int*   bsums   = (int*)alloc((size_t)NB * 4);
    int*   csr     = (int*)alloc((size_t)E * 4);
    float* hA      = (float*)alloc((size_t)N * 64 * 4);
    float* hB      = (float*)alloc((size_t)N * 64 * 4);
    (void)ws_size; (void)n_in; (void)out_size;

    hipMemsetAsync(deg, 0, (size_t)N * 4, stream);
    int eb = (E + 255) / 256;
    k_count<<<eb, 256, 0, stream>>>(edst, deg, E);
    k_blocksum<<<NB, 256, 0, stream>>>(deg, bsums, N);
    k_scantop<<<1, 256, 0, stream>>>(bsums, NB);
    k_scanfinal<<<NB, 256, 0, stream>>>(deg, bsums, offsets, cursor, inv_cnt, N, E);
    k_scatter<<<eb, 256, 0, stream>>>(esrc, edst, cursor, csr, E);

    auto blocksFor = [](int n, int npb) {
        int b = (n + npb - 1) / npb;
        return b < 2048 ? b : 2048;
    };
    k_level<3, 32, 32, 36><<<blocksFor(N, 64), 512, 0, stream>>>(raw, hA, offsets, csr, inv_cnt, Wa1, We1, N);
    k_level<32, 32, 64, 36><<<blocksFor(N, 64), 512, 0, stream>>>(hA, hB, offsets, csr, inv_cnt, Wa2, We2, N);
    k_level<64, 64, 64, 68><<<blocksFor(N, 64), 512, 0, stream>>>(hB, hA, offsets, csr, inv_cnt, Wa3, We3, N);
    k_level<64, 32, 32, 68><<<blocksFor(N, 64), 512, 0, stream>>>(hA, hB, offsets, csr, inv_cnt, Wa4, We4, N);

    k_out<<<(B * 40 + 255) / 256, 256, 0, stream>>>(hB, nodes, Wout, out, B);
}

// Round 4
// 388.944 us; speedup vs baseline: 2.6246x; 2.6246x over previous
//
#include <hip/hip_runtime.h>

// GraphSAGE forward: CSR build (count/scan/scatter) + 4 fused level kernels
// (mean-agg + 2 register-tiled small GEMMs) + output projection. All f32.
//
// Gather (round-2 proven pattern): GSIZE-lane groups per node; indices
// prefetched lane-parallel and shfl-broadcast; all GSIZE lanes read the SAME
// neighbor row so each vmem instruction touches NPG full contiguous rows
// (d=64: 4 rows x 256B). NO interleaved/strided row reads (round-3 regression:
// FETCH 80->636MB from fragmented per-instruction access).
//
// GEMMs (round-3 register tiling): lane=(node-part, col-group of OW floats);
// per k: 1 broadcast ds_read_b128 (weights) + NACC broadcast ds_read_b32 (m)
// + OW*NACC fmac. sM/sA share one wave-private padded LDS slab (reads precede
// writes in program order; wave lockstep makes this safe).

__device__ inline void f4acc(float4& a, const float4& b) {
    a.x += b.x; a.y += b.y; a.z += b.z; a.w += b.w;
}

__global__ __launch_bounds__(256) void k_count(const int* __restrict__ edst,
                                               int* __restrict__ deg, int E) {
    int t = blockIdx.x * blockDim.x + threadIdx.x;
    if (t < E) atomicAdd(&deg[edst[t]], 1);
}

__global__ __launch_bounds__(256) void k_blocksum(const int* __restrict__ deg,
                                                  int* __restrict__ bsums, int N) {
    __shared__ int s[256];
    int t = threadIdx.x;
    int base = blockIdx.x * 1024 + t * 4;
    int v = 0;
#pragma unroll
    for (int j = 0; j < 4; j++) { int idx = base + j; if (idx < N) v += deg[idx]; }
    s[t] = v; __syncthreads();
    for (int o = 128; o > 0; o >>= 1) { if (t < o) s[t] += s[t + o]; __syncthreads(); }
    if (t == 0) bsums[blockIdx.x] = s[0];
}

__global__ __launch_bounds__(256) void k_scantop(int* __restrict__ bsums, int NB) {
    __shared__ int s[256];
    int t = threadIdx.x;
    int v = (t < NB) ? bsums[t] : 0;
    s[t] = v; __syncthreads();
    for (int o = 1; o < 256; o <<= 1) {
        int x = (t >= o) ? s[t - o] : 0;
        __syncthreads();
        s[t] += x;
        __syncthreads();
    }
    if (t < NB) bsums[t] = s[t] - v;
}

__global__ __launch_bounds__(256) void k_scanfinal(const int* __restrict__ deg,
                                                   const int* __restrict__ bsums,
                                                   int* __restrict__ offsets,
                                                   int* __restrict__ cursor,
                                                   float* __restrict__ inv_cnt,
                                                   int N, int E) {
    __shared__ int s[256];
    int t = threadIdx.x, b = blockIdx.x;
    int base = b * 1024 + t * 4;
    int d[4]; int lsum = 0;
#pragma unroll
    for (int j = 0; j < 4; j++) { int idx = base + j; d[j] = (idx < N) ? deg[idx] : 0; lsum += d[j]; }
    s[t] = lsum; __syncthreads();
    for (int o = 1; o < 256; o <<= 1) {
        int x = (t >= o) ? s[t - o] : 0;
        __syncthreads();
        s[t] += x;
        __syncthreads();
    }
    int p = bsums[b] + s[t] - lsum;
#pragma unroll
    for (int j = 0; j < 4; j++) {
        int idx = base + j;
        if (idx < N) {
            offsets[idx] = p;
            cursor[idx] = p;
            inv_cnt[idx] = 1.0f / (float)(d[j] > 0 ? d[j] : 1);
            p += d[j];
        }
    }
    if (b == 0 && t == 0) offsets[N] = E;
}

__global__ __launch_bounds__(256) void k_scatter(const int* __restrict__ esrc,
                                                 const int* __restrict__ edst,
                                                 int* __restrict__ cursor,
                                                 int* __restrict__ csr, int E) {
    int t = blockIdx.x * blockDim.x + threadIdx.x;
    if (t < E) {
        int d = edst[t];
        int pos = atomicAdd(&cursor[d], 1);
        csr[pos] = esrc[t];
    }
}

// Register-tiled wave GEMM: [NPG nodes x DC cols] = wMA[NPG][K] @ W[K][DC].
// Lane covers OW cols of NACC nodes. All loop indices compile-time (rule #20).
template <int K, int DC, int NPG, int PADM, int OW>
__device__ inline void wave_gemm_lds(const float* wMA, const float* sW,
                                     float* outLDS, int lane) {
    constexpr int CQ = DC / OW;
    constexpr int PARTS = 64 / CQ;
    constexpr int NACC = NPG / PARTS;
    static_assert(NACC >= 1 && NACC * PARTS == NPG, "tiling mismatch");
    const int q = lane % CQ;
    const int part = lane / CQ;
    float acc[NACC][OW] = {};
#pragma unroll
    for (int k = 0; k < K; ++k) {
        float w[OW];
        if constexpr (OW == 4) *(float4*)w = *(const float4*)&sW[k * DC + 4 * q];
        else                   *(float2*)w = *(const float2*)&sW[k * DC + 2 * q];
#pragma unroll
        for (int j = 0; j < NACC; ++j) {
            float mv = wMA[(part + j * PARTS) * PADM + k];
#pragma unroll
            for (int o = 0; o < OW; ++o) acc[j][o] += mv * w[o];
        }
    }
#pragma unroll
    for (int j = 0; j < NACC; ++j) {
        float r[OW];
#pragma unroll
        for (int o = 0; o < OW; ++o) r[o] = fmaxf(acc[j][o], 0.f);
        if constexpr (OW == 4) *(float4*)&outLDS[(part + j * PARTS) * PADM + 4 * q] = *(float4*)r;
        else                   *(float2*)&outLDS[(part + j * PARTS) * PADM + 2 * q] = *(float2*)r;
    }
}

template <int K, int DC, int NPG, int PADM, int OW>
__device__ inline void wave_gemm_out(const float* wMA, const float* sW,
                                     float* __restrict__ dst, int nodebase, int N,
                                     int lane) {
    constexpr int CQ = DC / OW;
    constexpr int PARTS = 64 / CQ;
    constexpr int NACC = NPG / PARTS;
    static_assert(NACC >= 1 && NACC * PARTS == NPG, "tiling mismatch");
    const int q = lane % CQ;
    const int part = lane / CQ;
    float acc[NACC][OW] = {};
#pragma unroll
    for (int k = 0; k < K; ++k) {
        float w[OW];
        if constexpr (OW == 4) *(float4*)w = *(const float4*)&sW[k * DC + 4 * q];
        else                   *(float2*)w = *(const float2*)&sW[k * DC + 2 * q];
#pragma unroll
        for (int j = 0; j < NACC; ++j) {
            float mv = wMA[(part + j * PARTS) * PADM + k];
#pragma unroll
            for (int o = 0; o < OW; ++o) acc[j][o] += mv * w[o];
        }
    }
#pragma unroll
    for (int j = 0; j < NACC; ++j) {
        int node = nodebase + part + j * PARTS;
        if (node < N) {
            float r[OW];
#pragma unroll
            for (int o = 0; o < OW; ++o) r[o] = fmaxf(acc[j][o], 0.f);
            if constexpr (OW == 4) *(float4*)&dst[(size_t)node * DC + 4 * q] = *(float4*)r;
            else                   *(float2*)&dst[(size_t)node * DC + 2 * q] = *(float2*)r;
        }
    }
}

template <int DIN, int DMID, int DOUT, int GSIZE, int PADM, int OWA, int OWH>
__global__ __launch_bounds__(512, 6) void k_level(
    const float* __restrict__ hprev, float* __restrict__ hnext,
    const int* __restrict__ offsets, const int* __restrict__ csr,
    const float* __restrict__ inv_cnt,
    const float* __restrict__ Wa, const float* __restrict__ We, int N) {
    constexpr int WAVES = 8;
    constexpr int NPG = 64 / GSIZE;   // nodes per wave
    constexpr int NPB = WAVES * NPG;  // nodes per block

    __shared__ alignas(16) float sWa[DIN * DMID];
    __shared__ alignas(16) float sWe[DMID * DOUT];
    __shared__ alignas(16) float sMA[NPB * PADM];

    for (int i = threadIdx.x; i < DIN * DMID; i += 512) sWa[i] = Wa[i];
    for (int i = threadIdx.x; i < DMID * DOUT; i += 512) sWe[i] = We[i];
    __syncthreads();

    const int lane = threadIdx.x & 63;
    const int wid  = threadIdx.x >> 6;
    const int g    = lane / GSIZE;        // node group within wave
    const int lg   = lane & (GSIZE - 1);
    const int srcb = g * GSIZE;
    float* wMA = sMA + (wid * NPG) * PADM;

    const int nodebase = blockIdx.x * NPB + wid * NPG;
    const int node = nodebase + g;

    // ---- gather + mean (group-broadcast rows: contiguous per instruction) ----
    if (node < N) {
        int start = offsets[node], end = offsets[node + 1];
        float4 acc4 = make_float4(0.f, 0.f, 0.f, 0.f);
        float acc1 = 0.f;
        for (int bb = start; bb < end; bb += GSIZE) {
            int cnt = min(GSIZE, end - bb);
            int sidx = (lg < cnt) ? csr[bb + lg] : 0;  // coalesced index prefetch
            int i = 0;
            for (; i + 4 <= cnt; i += 4) {
                int s0 = __shfl(sidx, srcb + i);
                int s1 = __shfl(sidx, srcb + i + 1);
                int s2 = __shfl(sidx, srcb + i + 2);
                int s3 = __shfl(sidx, srcb + i + 3);
                if constexpr (DIN >= 32) {
                    const float4* r0 = (const float4*)(hprev + (size_t)s0 * DIN);
                    const float4* r1 = (const float4*)(hprev + (size_t)s1 * DIN);
                    const float4* r2 = (const float4*)(hprev + (size_t)s2 * DIN);
                    const float4* r3 = (const float4*)(hprev + (size_t)s3 * DIN);
                    f4acc(acc4, r0[lg]);
                    f4acc(acc4, r1[lg]);
                    f4acc(acc4, r2[lg]);
                    f4acc(acc4, r3[lg]);
                } else {
                    if (lg < DIN) {
                        acc1 += hprev[(size_t)s0 * DIN + lg];
                        acc1 += hprev[(size_t)s1 * DIN + lg];
                        acc1 += hprev[(size_t)s2 * DIN + lg];
                        acc1 += hprev[(size_t)s3 * DIN + lg];
                    }
                }
            }
            for (; i < cnt; ++i) {
                int s0 = __shfl(sidx, srcb + i);
                if constexpr (DIN >= 32) {
                    const float4* r0 = (const float4*)(hprev + (size_t)s0 * DIN);
                    f4acc(acc4, r0[lg]);
                } else {
                    if (lg < DIN) acc1 += hprev[(size_t)s0 * DIN + lg];
                }
            }
        }
        float ic = inv_cnt[node];
        if constexpr (DIN >= 32) {
            acc4.x *= ic; acc4.y *= ic; acc4.z *= ic; acc4.w *= ic;
            *(float4*)&wMA[g * PADM + 4 * lg] = acc4;
        } else {
            if (lg < DIN) wMA[g * PADM + lg] = acc1 * ic;
        }
    }

    // ---- a = relu(m @ Wa) ----  (wave-private slab; reads precede writes)
    wave_gemm_lds<DIN, DMID, NPG, PADM, OWA>(wMA, sWa, wMA, lane);
    // ---- h = relu(a @ We) -> global ----
    wave_gemm_out<DMID, DOUT, NPG, PADM, OWH>(wMA, sWe, hnext, nodebase, N, lane);
}

__global__ __launch_bounds__(256) void k_out(const float* __restrict__ h,
                                             const int* __restrict__ nodes,
                                             const float* __restrict__ Wout,
                                             float* __restrict__ out, int B) {
    __shared__ float sW[32 * 40];
    for (int i = threadIdx.x; i < 32 * 40; i += blockDim.x) sW[i] = Wout[i];
    __syncthreads();
    int t = blockIdx.x * blockDim.x + threadIdx.x;
    if (t >= B * 40) return;
    int i = t / 40, c = t - i * 40;
    const float* e = h + (long)nodes[i] * 32;
    float s = 0.f;
#pragma unroll
    for (int k = 0; k < 32; k++) s += e[k] * sW[k * 40 + c];
    out[t] = s;
}

extern "C" void kernel_launch(void* const* d_in, const int* in_sizes, int n_in,
                              void* d_out, int out_size, void* d_ws, size_t ws_size,
                              hipStream_t stream) {
    const float* raw  = (const float*)d_in[0];
    const int* nodes  = (const int*)d_in[1];
    const int* esrc   = (const int*)d_in[2];
    const int* edst   = (const int*)d_in[3];
    const float* Wa1 = (const float*)d_in[4];
    const float* Wa2 = (const float*)d_in[5];
    const float* Wa3 = (const float*)d_in[6];
    const float* Wa4 = (const float*)d_in[7];
    const float* We1 = (const float*)d_in[8];
    const float* We2 = (const float*)d_in[9];
    const float* We3 = (const float*)d_in[10];
    const float* We4 = (const float*)d_in[11];
    const float* Wout = (const float*)d_in[12];
    float* out = (float*)d_out;

    int N = in_sizes[1];   // 50000
    int E = in_sizes[2];   // 850000
    int B = N;

    char* p = (char*)d_ws;
    auto alloc = [&](size_t bytes) -> char* {
        char* r = p;
        p += (bytes + 255) & ~(size_t)255;
        return r;
    };
    int*   deg     = (int*)alloc((size_t)N * 4);
    int*   offsets = (int*)alloc((size_t)(N + 1) * 4);
    int*   cursor  = (int*)alloc((size_t)N * 4);
    float* inv_cnt = (float*)alloc((size_t)N * 4);
    int NB = (N + 1023) / 1024;
    int*   bsums   = (int*)alloc((size_t)NB * 4);
    int*   csr     = (int*)alloc((size_t)E * 4);
    float* hA      = (float*)alloc((size_t)N * 64 * 4);
    float* hB      = (float*)alloc((size_t)N * 64 * 4);
    (void)ws_size; (void)n_in; (void)out_size;

    hipMemsetAsync(deg, 0, (size_t)N * 4, stream);
    int eb = (E + 255) / 256;
    k_count<<<eb, 256, 0, stream>>>(edst, deg, E);
    k_blocksum<<<NB, 256, 0, stream>>>(deg, bsums, N);
    k_scantop<<<1, 256, 0, stream>>>(bsums, NB);
    k_scanfinal<<<NB, 256, 0, stream>>>(deg, bsums, offsets, cursor, inv_cnt, N, E);
    k_scatter<<<eb, 256, 0, stream>>>(esrc, edst, cursor, csr, E);

    auto blocksFor = [](int n, int npb) { return (n + npb - 1) / npb; };
    // L1: NPG=16 -> NPB=128; L2: NPG=8 -> 64; L3/L4: NPG=4 -> 32.
    k_level<3, 32, 32, 4, 36, 4, 4><<<blocksFor(N, 128), 512, 0, stream>>>(raw, hA, offsets, csr, inv_cnt, Wa1, We1, N);
    k_level<32, 32, 64, 8, 36, 4, 4><<<blocksFor(N, 64), 512, 0, stream>>>(hA, hB, offsets, csr, inv_cnt, Wa2, We2, N);
    k_level<64, 64, 64, 16, 68, 4, 4><<<blocksFor(N, 32), 512, 0, stream>>>(hB, hA, offsets, csr, inv_cnt, Wa3, We3, N);
    k_level<64, 32, 32, 16, 68, 2, 2><<<blocksFor(N, 32), 512, 0, stream>>>(hA, hB, offsets, csr, inv_cnt, Wa4, We4, N);

    k_out<<<(B * 40 + 255) / 256, 256, 0, stream>>>(hB, nodes, Wout, out, B);
}

// Round 5
// 293.175 us; speedup vs baseline: 3.4820x; 1.3267x over previous
//
#include <hip/hip_runtime.h>

// GraphSAGE forward. CSR build + 4 fused level kernels + output projection.
//
// Key structure (round-5):
//  - Gather uses the round-2-PROVEN geometry: GSIZE=d/2 lanes per node read one
//    full contiguous row per vmem instruction as float2; indices prefetched
//    lane-parallel and shfl-broadcast; 4-edge unroll; 2048-cap grid-stride.
//    (Round-3/4 variants fragmented access or thrashed L2: FETCH 199-636MB.)
//  - GEMM phases are block-cooperative register-tiled (barrier-separated),
//    reading m/a from padded LDS slabs (PAD=d+2 -> <=2-way banks), weights
//    broadcast from LDS, float2 everywhere.
//  - Algebraic cut: mean_agg(h)@Wa == mean_agg(h@Wa). L3 emits g=h3@Wa4
//    (N x 32) ONLY; L4 gathers 128B g-rows and skips its Wa GEMM entirely.

__global__ __launch_bounds__(256) void k_count(const int* __restrict__ edst,
                                               int* __restrict__ deg, int E) {
    int t = blockIdx.x * blockDim.x + threadIdx.x;
    if (t < E) atomicAdd(&deg[edst[t]], 1);
}

__global__ __launch_bounds__(256) void k_blocksum(const int* __restrict__ deg,
                                                  int* __restrict__ bsums, int N) {
    __shared__ int s[256];
    int t = threadIdx.x;
    int base = blockIdx.x * 1024 + t * 4;
    int v = 0;
#pragma unroll
    for (int j = 0; j < 4; j++) { int idx = base + j; if (idx < N) v += deg[idx]; }
    s[t] = v; __syncthreads();
    for (int o = 128; o > 0; o >>= 1) { if (t < o) s[t] += s[t + o]; __syncthreads(); }
    if (t == 0) bsums[blockIdx.x] = s[0];
}

__global__ __launch_bounds__(256) void k_scantop(int* __restrict__ bsums, int NB) {
    __shared__ int s[256];
    int t = threadIdx.x;
    int v = (t < NB) ? bsums[t] : 0;
    s[t] = v; __syncthreads();
    for (int o = 1; o < 256; o <<= 1) {
        int x = (t >= o) ? s[t - o] : 0;
        __syncthreads();
        s[t] += x;
        __syncthreads();
    }
    if (t < NB) bsums[t] = s[t] - v;
}

__global__ __launch_bounds__(256) void k_scanfinal(const int* __restrict__ deg,
                                                   const int* __restrict__ bsums,
                                                   int* __restrict__ offsets,
                                                   int* __restrict__ cursor,
                                                   float* __restrict__ inv_cnt,
                                                   int N, int E) {
    __shared__ int s[256];
    int t = threadIdx.x, b = blockIdx.x;
    int base = b * 1024 + t * 4;
    int d[4]; int lsum = 0;
#pragma unroll
    for (int j = 0; j < 4; j++) { int idx = base + j; d[j] = (idx < N) ? deg[idx] : 0; lsum += d[j]; }
    s[t] = lsum; __syncthreads();
    for (int o = 1; o < 256; o <<= 1) {
        int x = (t >= o) ? s[t - o] : 0;
        __syncthreads();
        s[t] += x;
        __syncthreads();
    }
    int p = bsums[b] + s[t] - lsum;
#pragma unroll
    for (int j = 0; j < 4; j++) {
        int idx = base + j;
        if (idx < N) {
            offsets[idx] = p;
            cursor[idx] = p;
            inv_cnt[idx] = 1.0f / (float)(d[j] > 0 ? d[j] : 1);
            p += d[j];
        }
    }
    if (b == 0 && t == 0) offsets[N] = E;
}

__global__ __launch_bounds__(256) void k_scatter(const int* __restrict__ esrc,
                                                 const int* __restrict__ edst,
                                                 int* __restrict__ cursor,
                                                 int* __restrict__ csr, int E) {
    int t = blockIdx.x * blockDim.x + threadIdx.x;
    if (t < E) {
        int d = edst[t];
        int pos = atomicAdd(&cursor[d], 1);
        csr[pos] = esrc[t];
    }
}

// One block = NPB nodes. Phases: gather-mean -> [A: relu(m@Wa) | relu(m)]
// -> H: relu(a@We) -> {global | stash} -> [G: h@Wg -> global].
template <int DIN, int DMID, int DOUT, int GSIZE, int PADM, int PADA,
          bool HAS_WA, int DG>
__global__ __launch_bounds__(512, 8) void k_level(
    const float* __restrict__ hprev, float* __restrict__ outbuf,
    const int* __restrict__ offsets, const int* __restrict__ csr,
    const float* __restrict__ inv_cnt,
    const float* __restrict__ Wa, const float* __restrict__ We,
    const float* __restrict__ Wg, int N) {
    constexpr int WAVES = 8;
    constexpr int NPG = 64 / GSIZE;   // nodes per wave
    constexpr int NPB = WAVES * NPG;  // nodes per block

    __shared__ alignas(16) float sWa[HAS_WA ? DIN * DMID : 1];
    __shared__ alignas(16) float sWe[DMID * DOUT];
    __shared__ alignas(16) float sWg[(DG > 0) ? DOUT * DG : 1];
    __shared__ alignas(16) float sM[NPB * PADM];
    __shared__ alignas(16) float sA[NPB * PADA];

    if constexpr (HAS_WA)
        for (int i = threadIdx.x; i < DIN * DMID; i += 512) sWa[i] = Wa[i];
    for (int i = threadIdx.x; i < DMID * DOUT; i += 512) sWe[i] = We[i];
    if constexpr (DG > 0)
        for (int i = threadIdx.x; i < DOUT * DG; i += 512) sWg[i] = Wg[i];
    __syncthreads();

    const int t    = threadIdx.x;
    const int lane = t & 63;
    const int wid  = t >> 6;
    const int g    = lane / GSIZE;
    const int lg   = lane % GSIZE;
    const int srcb = g * GSIZE;
    const int slot = wid * NPG + g;

    for (int base = blockIdx.x * NPB; base < N; base += gridDim.x * NPB) {
        int node = base + slot;
        // ---- gather + mean (full contiguous row per instruction, float2) ----
        if (node < N) {
            int start = offsets[node], end = offsets[node + 1];
            if constexpr (DIN >= 32) {
                float2 acc = make_float2(0.f, 0.f);
                const float2* hp = (const float2*)hprev;
                for (int bb = start; bb < end; bb += GSIZE) {
                    int cnt = min(GSIZE, end - bb);
                    int sidx = (lg < cnt) ? csr[bb + lg] : 0;
                    int i = 0;
                    for (; i + 4 <= cnt; i += 4) {
                        int s0 = __shfl(sidx, srcb + i);
                        int s1 = __shfl(sidx, srcb + i + 1);
                        int s2 = __shfl(sidx, srcb + i + 2);
                        int s3 = __shfl(sidx, srcb + i + 3);
                        float2 v0 = hp[(size_t)s0 * (DIN / 2) + lg];
                        float2 v1 = hp[(size_t)s1 * (DIN / 2) + lg];
                        float2 v2 = hp[(size_t)s2 * (DIN / 2) + lg];
                        float2 v3 = hp[(size_t)s3 * (DIN / 2) + lg];
                        acc.x += (v0.x + v1.x) + (v2.x + v3.x);
                        acc.y += (v0.y + v1.y) + (v2.y + v3.y);
                    }
                    for (; i < cnt; ++i) {
                        int s0 = __shfl(sidx, srcb + i);
                        float2 v0 = hp[(size_t)s0 * (DIN / 2) + lg];
                        acc.x += v0.x; acc.y += v0.y;
                    }
                }
                float ic = inv_cnt[node];
                *(float2*)&sM[slot * PADM + 2 * lg] = make_float2(acc.x * ic, acc.y * ic);
            } else {  // DIN == 3
                float a1 = 0.f;
                for (int bb = start; bb < end; bb += GSIZE) {
                    int cnt = min(GSIZE, end - bb);
                    int sidx = (lg < cnt) ? csr[bb + lg] : 0;
                    int i = 0;
                    for (; i + 4 <= cnt; i += 4) {
                        int s0 = __shfl(sidx, srcb + i);
                        int s1 = __shfl(sidx, srcb + i + 1);
                        int s2 = __shfl(sidx, srcb + i + 2);
                        int s3 = __shfl(sidx, srcb + i + 3);
                        if (lg < DIN) {
                            a1 += hprev[(size_t)s0 * DIN + lg] + hprev[(size_t)s1 * DIN + lg]
                                + hprev[(size_t)s2 * DIN + lg] + hprev[(size_t)s3 * DIN + lg];
                        }
                    }
                    for (; i < cnt; ++i) {
                        int s0 = __shfl(sidx, srcb + i);
                        if (lg < DIN) a1 += hprev[(size_t)s0 * DIN + lg];
                    }
                }
                if (lg < DIN) sM[slot * PADM + lg] = a1 * inv_cnt[node];
            }
        }
        __syncthreads();

        // ---- phase A: sA = relu(sM @ Wa)  (or relu-copy when !HAS_WA) ----
        if constexpr (HAS_WA) {
            constexpr int CQ = DMID / 2;
            constexpr int TOT = NPB * CQ;
            constexpr int NJ = (TOT + 511) / 512;
#pragma unroll
            for (int j = 0; j < NJ; ++j) {
                int idx = t + j * 512;
                if (TOT % 512 == 0 || idx < TOT) {
                    int r = idx / CQ, q = idx % CQ;
                    float ax = 0.f, ay = 0.f;
#pragma unroll
                    for (int k = 0; k < DIN; ++k) {
                        float mv = sM[r * PADM + k];
                        float2 w = *(const float2*)&sWa[k * DMID + 2 * q];
                        ax += mv * w.x; ay += mv * w.y;
                    }
                    *(float2*)&sA[r * PADA + 2 * q] =
                        make_float2(fmaxf(ax, 0.f), fmaxf(ay, 0.f));
                }
            }
        } else {
            constexpr int CQ = DMID / 2;
            constexpr int TOT = NPB * CQ;
            constexpr int NJ = (TOT + 511) / 512;
#pragma unroll
            for (int j = 0; j < NJ; ++j) {
                int idx = t + j * 512;
                if (TOT % 512 == 0 || idx < TOT) {
                    int r = idx / CQ, q = idx % CQ;
                    float2 v = *(const float2*)&sM[r * PADM + 2 * q];
                    *(float2*)&sA[r * PADA + 2 * q] =
                        make_float2(fmaxf(v.x, 0.f), fmaxf(v.y, 0.f));
                }
            }
        }
        __syncthreads();

        // ---- phase H: h = relu(sA @ We) -> global (or stash for phase G) ----
        {
            constexpr int CQ = DOUT / 2;
            constexpr int TOT = NPB * CQ;
            constexpr int NJ = (TOT + 511) / 512;
#pragma unroll
            for (int j = 0; j < NJ; ++j) {
                int idx = t + j * 512;
                if (TOT % 512 == 0 || idx < TOT) {
                    int r = idx / CQ, q = idx % CQ;
                    float hx = 0.f, hy = 0.f;
#pragma unroll
                    for (int k = 0; k < DMID; ++k) {
                        float av = sA[r * PADA + k];
                        float2 w = *(const float2*)&sWe[k * DOUT + 2 * q];
                        hx += av * w.x; hy += av * w.y;
                    }
                    hx = fmaxf(hx, 0.f); hy = fmaxf(hy, 0.f);
                    if constexpr (DG > 0) {
                        *(float2*)&sM[r * PADM + 2 * q] = make_float2(hx, hy);
                    } else {
                        int nd = base + r;
                        if (nd < N)
                            *(float2*)&outbuf[(size_t)nd * DOUT + 2 * q] =
                                make_float2(hx, hy);
                    }
                }
            }
        }

        // ---- phase G (L3 only): g = h @ Wg -> global (no relu) ----
        if constexpr (DG > 0) {
            __syncthreads();
            constexpr int CQ = DG / 2;
            constexpr int TOT = NPB * CQ;
            constexpr int NJ = (TOT + 511) / 512;
#pragma unroll
            for (int j = 0; j < NJ; ++j) {
                int idx = t + j * 512;
                if (TOT % 512 == 0 || idx < TOT) {
                    int r = idx / CQ, q = idx % CQ;
                    float gx = 0.f, gy = 0.f;
#pragma unroll
                    for (int k = 0; k < DOUT; ++k) {
                        float hv = sM[r * PADM + k];
                        float2 w = *(const float2*)&sWg[k * DG + 2 * q];
                        gx += hv * w.x; gy += hv * w.y;
                    }
                    int nd = base + r;
                    if (nd < N)
                        *(float2*)&outbuf[(size_t)nd * DG + 2 * q] =
                            make_float2(gx, gy);
                }
            }
        }
        __syncthreads();  // protect slab reuse next tile
    }
}

__global__ __launch_bounds__(256) void k_out(const float* __restrict__ h,
                                             const int* __restrict__ nodes,
                                             const float* __restrict__ Wout,
                                             float* __restrict__ out, int B) {
    __shared__ float sW[32 * 40];
    for (int i = threadIdx.x; i < 32 * 40; i += blockDim.x) sW[i] = Wout[i];
    __syncthreads();
    int t = blockIdx.x * blockDim.x + threadIdx.x;
    if (t >= B * 40) return;
    int i = t / 40, c = t - i * 40;
    const float* e = h + (long)nodes[i] * 32;
    float s = 0.f;
#pragma unroll
    for (int k = 0; k < 32; k++) s += e[k] * sW[k * 40 + c];
    out[t] = s;
}

extern "C" void kernel_launch(void* const* d_in, const int* in_sizes, int n_in,
                              void* d_out, int out_size, void* d_ws, size_t ws_size,
                              hipStream_t stream) {
    const float* raw  = (const float*)d_in[0];
    const int* nodes  = (const int*)d_in[1];
    const int* esrc   = (const int*)d_in[2];
    const int* edst   = (const int*)d_in[3];
    const float* Wa1 = (const float*)d_in[4];
    const float* Wa2 = (const float*)d_in[5];
    const float* Wa3 = (const float*)d_in[6];
    const float* Wa4 = (const float*)d_in[7];
    const float* We1 = (const float*)d_in[8];
    const float* We2 = (const float*)d_in[9];
    const float* We3 = (const float*)d_in[10];
    const float* We4 = (const float*)d_in[11];
    const float* Wout = (const float*)d_in[12];
    float* out = (float*)d_out;

    int N = in_sizes[1];   // 50000
    int E = in_sizes[2];   // 850000
    int B = N;

    char* p = (char*)d_ws;
    auto alloc = [&](size_t bytes) -> char* {
        char* r = p;
        p += (bytes + 255) & ~(size_t)255;
        return r;
    };
    int*   deg     = (int*)alloc((size_t)N * 4);
    int*   offsets = (int*)alloc((size_t)(N + 1) * 4);
    int*   cursor  = (int*)alloc((size_t)N * 4);
    float* inv_cnt = (float*)alloc((size_t)N * 4);
    int NB = (N + 1023) / 1024;
    int*   bsums   = (int*)alloc((size_t)NB * 4);
    int*   csr     = (int*)alloc((size_t)E * 4);
    float* hA      = (float*)alloc((size_t)N * 64 * 4);
    float* hB      = (float*)alloc((size_t)N * 64 * 4);
    (void)ws_size; (void)n_in; (void)out_size;

    hipMemsetAsync(deg, 0, (size_t)N * 4, stream);
    int eb = (E + 255) / 256;
    k_count<<<eb, 256, 0, stream>>>(edst, deg, E);
    k_blocksum<<<NB, 256, 0, stream>>>(deg, bsums, N);
    k_scantop<<<1, 256, 0, stream>>>(bsums, NB);
    k_scanfinal<<<NB, 256, 0, stream>>>(deg, bsums, offsets, cursor, inv_cnt, N, E);
    k_scatter<<<eb, 256, 0, stream>>>(esrc, edst, cursor, csr, E);

    auto blocksFor = [](int n, int npb) {
        int b = (n + npb - 1) / npb;
        return b < 2048 ? b : 2048;
    };
    // L1: raw(3) -> h1(32) in hB
    k_level<3, 32, 32, 4, 4, 34, true, 0>
        <<<blocksFor(N, 128), 512, 0, stream>>>(raw, hB, offsets, csr, inv_cnt,
                                                Wa1, We1, nullptr, N);
    // L2: h1(32) -> h2(64) in hA
    k_level<32, 32, 64, 16, 34, 34, true, 0>
        <<<blocksFor(N, 32), 512, 0, stream>>>(hB, hA, offsets, csr, inv_cnt,
                                               Wa2, We2, nullptr, N);
    // L3: h2(64) -> h3(64) -> emit g = h3@Wa4 (32) ONLY, into hB
    k_level<64, 64, 64, 32, 66, 66, true, 32>
        <<<blocksFor(N, 16), 512, 0, stream>>>(hA, hB, offsets, csr, inv_cnt,
                                               Wa3, We3, Wa4, N);
    // L4: gather g(32), a=relu(m) (Wa absorbed), h4 = relu(a@We4) (32) in hA
    k_level<32, 32, 32, 16, 34, 34, false, 0>
        <<<blocksFor(N, 32), 512, 0, stream>>>(hB, hA, offsets, csr, inv_cnt,
                                               nullptr, We4, nullptr, N);

    k_out<<<(B * 40 + 255) / 256, 256, 0, stream>>>(hA, nodes, Wout, out, B);
}